// Round 1
// baseline (116.554 us; speedup 1.0000x reference)
//
#include <hip/hip_runtime.h>
#include <math.h>

#define SLOPE 0.1f
#define B_ 16
#define C_ 64
#define H_ 160
#define W_ 160
#define HW_ (H_*W_)

// ws layout (floats):
//   [0, 9216)        k[b][c][9]
//   [9216, 10240)    att[b][c]
//   [10240, 14336)   WcT[c][o]  (transposed Wc)
#define WS_K   0
#define WS_ATT 9216
#define WS_WCT 10240

__device__ __forceinline__ float lrelu(float x) { return fmaxf(x, SLOPE * x); }

__global__ __launch_bounds__(64) void prep_kernel(
    const float* __restrict__ deg,
    const float* __restrict__ W1,
    const float* __restrict__ W2,
    const float* __restrict__ Wc,
    const float* __restrict__ Wd1,
    const float* __restrict__ Wd2,
    float* __restrict__ ws) {
  const int b = blockIdx.x;   // 0..15
  const int j = threadIdx.x;  // 0..63
  __shared__ float sd[64], sh[64], sa[8];
  sd[j] = deg[b * 64 + j];
  __syncthreads();

  // h_j = lrelu(d . W1[j,:])
  float acc = 0.f;
  for (int i = 0; i < 64; ++i) acc = fmaf(sd[i], W1[j * 64 + i], acc);
  sh[j] = lrelu(acc);

  // a_r = lrelu(d . Wd1[r,:])   (threads 0..7)
  if (j < 8) {
    float s = 0.f;
    for (int i = 0; i < 64; ++i) s = fmaf(sd[i], Wd1[j * 64 + i], s);
    sa[j] = lrelu(s);
  }
  __syncthreads();

  // k[b][j][t] = sum_l h_l * W2[(j*9+t), l]
  float kv[9];
#pragma unroll
  for (int t = 0; t < 9; ++t) kv[t] = 0.f;
  for (int l = 0; l < 64; ++l) {
    float hl = sh[l];
#pragma unroll
    for (int t = 0; t < 9; ++t) kv[t] = fmaf(hl, W2[(j * 9 + t) * 64 + l], kv[t]);
  }
#pragma unroll
  for (int t = 0; t < 9; ++t) ws[WS_K + (b * 64 + j) * 9 + t] = kv[t];

  // att[b][j] = sigmoid(Wd2[j,:] . a)
  float s2 = 0.f;
#pragma unroll
  for (int r = 0; r < 8; ++r) s2 = fmaf(Wd2[j * 8 + r], sa[r], s2);
  ws[WS_ATT + b * 64 + j] = 1.f / (1.f + __expf(-s2));

  // WcT (block 0 only; same value every call -> deterministic)
  if (b == 0) {
    for (int c = 0; c < 64; ++c) ws[WS_WCT + c * 64 + j] = Wc[j * 64 + c];
  }
}

// Fused: depthwise 3x3 conv (per-(b,c) kernel) -> lrelu -> 64x64 channel mix
//        + bias + feat*att residual.
// Block = 256 threads = 8 rows x 32 cols tile of one batch image.
// Each thread owns one pixel, acc[64] output channels in registers.
__global__ __launch_bounds__(256) void main_kernel(
    const float* __restrict__ feat,
    const float* __restrict__ bc,
    const float* __restrict__ ws,
    float* __restrict__ out) {
  const int tx = blockIdx.x;  // 0..4
  const int ty = blockIdx.y;  // 0..19
  const int b  = blockIdx.z;  // 0..15
  const int px = threadIdx.x & 31;
  const int py = threadIdx.x >> 5;
  const int x = tx * 32 + px;
  const int y = ty * 8 + py;

  const float* __restrict__ kk  = ws + WS_K + b * 576;   // uniform -> s_load
  const float* __restrict__ att = ws + WS_ATT + b * 64;  // uniform -> s_load
  const float* __restrict__ wct = ws + WS_WCT;           // uniform -> s_load

  // Precompute tap offsets (clamped, always in-bounds) + zero-pad masks.
  int off[9];
  float msk[9];
#pragma unroll
  for (int t = 0; t < 9; ++t) {
    const int dy = t / 3 - 1, dx = t % 3 - 1;
    const int yy = y + dy, xx = x + dx;
    const bool v = (yy >= 0) && (yy < H_) && (xx >= 0) && (xx < W_);
    const int ycl = min(max(yy, 0), H_ - 1);
    const int xcl = min(max(xx, 0), W_ - 1);
    off[t] = ycl * W_ + xcl;
    msk[t] = v ? 1.f : 0.f;
  }

  float acc[64];
#pragma unroll
  for (int o = 0; o < 64; ++o) acc[o] = bc[o];

  const float* __restrict__ plane0 = feat + (size_t)(b * 64) * HW_;

  for (int c = 0; c < 64; ++c) {
    const float* __restrict__ p = plane0 + (size_t)c * HW_;
    float s = 0.f;
#pragma unroll
    for (int t = 0; t < 9; ++t) {
      const float v = p[off[t]] * msk[t];  // zero padding via mask
      s = fmaf(v, kk[c * 9 + t], s);       // kk uniform -> SGPR operand
    }
    const float tv = lrelu(s);
#pragma unroll
    for (int o = 0; o < 64; ++o)
      acc[o] = fmaf(wct[c * 64 + o], tv, acc[o]);  // wct uniform -> SGPR operand
  }

  // Residual (feat * att) + store.
  const int pix = y * W_ + x;
  const float* __restrict__ inp = plane0 + pix;
  float* __restrict__ outp = out + (size_t)(b * 64) * HW_ + pix;
#pragma unroll
  for (int o = 0; o < 64; ++o) {
    const float cf = inp[(size_t)o * HW_];
    outp[(size_t)o * HW_] = fmaf(cf, att[o], acc[o]);
  }
}

extern "C" void kernel_launch(void* const* d_in, const int* in_sizes, int n_in,
                              void* d_out, int out_size, void* d_ws, size_t ws_size,
                              hipStream_t stream) {
  const float* feat = (const float*)d_in[0];
  const float* deg  = (const float*)d_in[1];
  const float* W1   = (const float*)d_in[2];
  const float* W2   = (const float*)d_in[3];
  const float* Wc   = (const float*)d_in[4];
  const float* bc   = (const float*)d_in[5];
  const float* Wd1  = (const float*)d_in[6];
  const float* Wd2  = (const float*)d_in[7];
  float* out = (float*)d_out;
  float* ws  = (float*)d_ws;

  prep_kernel<<<dim3(B_), dim3(64), 0, stream>>>(deg, W1, W2, Wc, Wd1, Wd2, ws);
  main_kernel<<<dim3(5, 20, B_), dim3(256), 0, stream>>>(feat, bc, ws, out);
}